// Round 2
// baseline (746.844 us; speedup 1.0000x reference)
//
#include <hip/hip_runtime.h>
#include <cstdint>

// Problem constants (from reference)
#define M_ROWS 8192
#define HIDDEN 4096
#define GROUP  128        // fp8 group size == HEAD_DIM
#define NGRP   32         // HIDDEN / GROUP
#define FP8MAX 448.0f
#define EPSV   1e-6f

using float4_t = __attribute__((ext_vector_type(4))) float;

// ---------------------------------------------------------------------------
// async global -> LDS, 16 bytes per lane. LDS dest is wave-uniform base +
// lane*16 (global_load_lds constraint); global source may be per-lane.
// ---------------------------------------------------------------------------
__device__ __forceinline__ void async_ld16(const void* g, void* l) {
    __builtin_amdgcn_global_load_lds(
        (const __attribute__((address_space(1))) void*)g,
        (__attribute__((address_space(3))) void*)l, 16, 0, 0);
}

// ---------------------------------------------------------------------------
// Kernel 1: relu(x), relu(z), per-head RMSNorm * norm_weight * silu(z),
// per-(row,head) fp8 e4m3 quantization.
// Layout: 32 lanes per head, 4 consecutive floats per lane (16B loads),
// 2 heads per wave, 8 heads per 256-thread block.
// a     : [M][HIDDEN] fp8 bytes (written as uint32 per lane)
// a_scT : [NGRP][M] fp32 scales, TRANSPOSED for coalesced GEMM staging
// ---------------------------------------------------------------------------
__global__ __launch_bounds__(256)
void act_quant_kernel(const float4_t* __restrict__ x, const float4_t* __restrict__ z,
                      const float* __restrict__ nw,
                      uint32_t* __restrict__ a, float* __restrict__ a_scT) {
    const int tid  = threadIdx.x;
    const int lane = tid & 63;
    const int l32  = lane & 31;          // lane within head
    const int sub  = lane >> 5;          // head within wave
    const int wv   = tid >> 6;
    const long gh  = (long)blockIdx.x * 8 + wv * 2 + sub;  // global head = row*32 + h
    const long row = gh >> 5;
    const int  h   = (int)(gh & 31);
    const long base4 = row * (HIDDEN / 4) + (long)h * 32 + l32;  // float4 index

    float4_t xv = x[base4];
    float4_t zv = z[base4];
    float g[4];
    float ss = 0.f;
    #pragma unroll
    for (int j = 0; j < 4; ++j) {
        float xr = fmaxf(xv[j], 0.f);    // relu
        g[j] = xr;
        ss += xr * xr;
    }
    // mean-of-squares over the 128-elem head: 5-step xor reduce within 32 lanes
    #pragma unroll
    for (int o = 16; o > 0; o >>= 1) ss += __shfl_xor(ss, o, 64);
    const float rstd = 1.0f / sqrtf(ss * (1.0f / 128.0f) + EPSV);

    const float4_t w4 = *(const float4_t*)(nw + l32 * 4);
    float am = 0.f;
    #pragma unroll
    for (int j = 0; j < 4; ++j) {
        float zr = fmaxf(zv[j], 0.f);                 // relu
        float si = zr / (1.f + expf(-zr));            // silu (zr>=0, safe)
        g[j] = g[j] * rstd * w4[j] * si;
        am = fmaxf(am, fabsf(g[j]));
    }
    // group absmax: 5-step xor reduce
    #pragma unroll
    for (int o = 16; o > 0; o >>= 1) am = fmaxf(am, __shfl_xor(am, o, 64));
    const float scale = fmaxf(am, 1e-12f) / FP8MAX;

    // quantize (exact division to match reference), HW RNE fp8 pack
    int p = __builtin_amdgcn_cvt_pk_fp8_f32(g[0] / scale, g[1] / scale, 0, false);
    p     = __builtin_amdgcn_cvt_pk_fp8_f32(g[2] / scale, g[3] / scale, p, true);
    a[base4] = (uint32_t)p;
    if (l32 == 0) a_scT[(long)h * M_ROWS + row] = scale;
}

// ---------------------------------------------------------------------------
// Kernel 2: per-(128,128)-block fp8 quantization of w.
// Block (jb,kb) handles w[jb*128 : +128][kb*128 : +128].
// wq   : [HIDDEN][HIDDEN] fp8 bytes (same layout as w: [j][k])
// w_sc : [NGRP][NGRP] fp32, index [jb][kb]
// ---------------------------------------------------------------------------
__global__ __launch_bounds__(256)
void w_quant_kernel(const float* __restrict__ w, uint8_t* __restrict__ wq,
                    float* __restrict__ w_sc) {
    const int jb = blockIdx.x, kb = blockIdx.y;
    const int tid  = threadIdx.x;
    const int lane = tid & 63;
    const int wv   = tid >> 6;
    const int r     = tid >> 1;          // 0..127 row within block
    const int cbase = (tid & 1) * 64;    // half-row per thread (64 elems)
    const float* src = w + (long)(jb * 128 + r) * HIDDEN + kb * 128 + cbase;

    float am = 0.f;
    #pragma unroll
    for (int i = 0; i < 16; ++i) {
        float4_t v = *(const float4_t*)(src + i * 4);
        am = fmaxf(am, fmaxf(fmaxf(fabsf(v[0]), fabsf(v[1])),
                             fmaxf(fabsf(v[2]), fabsf(v[3]))));
    }
    #pragma unroll
    for (int o = 32; o > 0; o >>= 1) am = fmaxf(am, __shfl_xor(am, o, 64));

    __shared__ float red[4];
    if (lane == 0) red[wv] = am;
    __syncthreads();
    am = fmaxf(fmaxf(red[0], red[1]), fmaxf(red[2], red[3]));
    const float scale = fmaxf(am, 1e-12f) / FP8MAX;
    if (tid == 0) w_sc[jb * NGRP + kb] = scale;

    uint8_t* dst = wq + (long)(jb * 128 + r) * HIDDEN + kb * 128 + cbase;
    #pragma unroll
    for (int i = 0; i < 16; ++i) {
        float4_t v = *(const float4_t*)(src + i * 4);   // L1/L2-hot re-read
        int p = __builtin_amdgcn_cvt_pk_fp8_f32(v[0] / scale, v[1] / scale, 0, false);
        p     = __builtin_amdgcn_cvt_pk_fp8_f32(v[2] / scale, v[3] / scale, p, true);
        *(uint32_t*)(dst + i * 4) = (uint32_t)p;
    }
}

// ---------------------------------------------------------------------------
// Kernel 3: blockwise-scaled fp8 GEMM.  C[n][j] = sum over 128-K groups of
// a_sc[n,kg]*w_sc[jb,kg] * (fp8 dot over the group).
// 128x128 C tile / block, 4 waves in 2x2, each wave 4x4 tiles of 16x16.
// BK = 128 = one scale group per staging iteration.
// LDS chunk placement XOR-swizzled: slot cs of row r holds global 16B-chunk
// cs^(r&7), so stride-128B fragment reads hit the wave64-structural
// 2-access/bank pattern (free) instead of a 16-way conflict.
// lAs holds a_sc[row,kg] PRE-MULTIPLIED by w_sc[jb,kg] (saves per-kg muls).
// ---------------------------------------------------------------------------
__global__ __launch_bounds__(256, 3)
void gemm_fp8_scaled(const uint8_t* __restrict__ A, const float* __restrict__ AsT,
                     const uint8_t* __restrict__ B, const float* __restrict__ Bs,
                     float* __restrict__ C) {
    constexpr int K = HIDDEN;
    __shared__ uint8_t lA[128 * 128];
    __shared__ uint8_t lB[128 * 128];
    __shared__ float   lAs[NGRP * 128];   // [kg][row], premultiplied by w_sc

    const int tid  = threadIdx.x;
    const int lane = tid & 63;
    const int wv   = tid >> 6;
    const long row0 = (long)blockIdx.x * 128;
    const long col0 = (long)blockIdx.y * 128;

    // stage combined scales: lAs[g*128+r] = AsT[g][row0+r] * Bs[jb][g]
    // coalesced: consecutive tids read consecutive rows of AsT
    for (int i = tid; i < NGRP * 128; i += 256) {
        int r = i & 127, g = i >> 7;
        lAs[g * 128 + r] = AsT[(long)g * M_ROWS + row0 + r] * Bs[blockIdx.y * NGRP + g];
    }

    const int m    = lane & 15;     // MFMA A-row / D-col index
    const int quad = lane >> 4;
    const int wm = (wv & 1) * 64;   // wave's 64x64 quadrant
    const int wn = (wv >> 1) * 64;

    const int srow = tid >> 3;      // staging: 32 rows per pass
    const int slot = tid & 7;       // staging: LDS chunk slot within row

    float4_t acc[4][4] = {};

    for (int kg = 0; kg < NGRP; ++kg) {
        // ---- stage A and B 128x128-byte tiles (swizzled chunk choice) ----
        #pragma unroll
        for (int p = 0; p < 4; ++p) {
            int r = p * 32 + srow;
            int c = slot ^ (r & 7);
            async_ld16(A + (row0 + r) * K + kg * 128 + c * 16,
                       &lA[p * 4096 + tid * 16]);
        }
        #pragma unroll
        for (int p = 0; p < 4; ++p) {
            int r = p * 32 + srow;
            int c = slot ^ (r & 7);
            async_ld16(B + (col0 + r) * K + kg * 128 + c * 16,
                       &lB[p * 4096 + tid * 16]);
        }
        __syncthreads();   // drains vmcnt (global_load_lds) + covers lAs on kg==0

        // ---- fp8 MFMA over the group into a partial accumulator ----
        float4_t part[4][4] = {};
        #pragma unroll
        for (int ks = 0; ks < 4; ++ks) {
            const int c16 = ks * 2 + (quad >> 1);
            const int hof = (quad & 1) * 8;
            long af[4], bf[4];
            #pragma unroll
            for (int t = 0; t < 4; ++t) {
                int r = wm + t * 16 + m;
                af[t] = *(const long*)&lA[r * 128 + ((c16 ^ (r & 7)) * 16) + hof];
            }
            #pragma unroll
            for (int t = 0; t < 4; ++t) {
                int r = wn + t * 16 + m;
                bf[t] = *(const long*)&lB[r * 128 + ((c16 ^ (r & 7)) * 16) + hof];
            }
            #pragma unroll
            for (int mt = 0; mt < 4; ++mt)
                #pragma unroll
                for (int nt = 0; nt < 4; ++nt)
                    part[mt][nt] = __builtin_amdgcn_mfma_f32_16x16x32_fp8_fp8(
                        af[mt], bf[nt], part[mt][nt], 0, 0, 0);
        }
        __syncthreads();   // LDS tiles free for next iteration

        // ---- fold combined group scale: acc += lAs[kg][row] * part ----
        #pragma unroll
        for (int mt = 0; mt < 4; ++mt) {
            // D rows for this lane: wm + mt*16 + quad*4 + reg, reg=0..3 (consecutive)
            float4_t s4 = *(const float4_t*)&lAs[kg * 128 + wm + mt * 16 + quad * 4];
            #pragma unroll
            for (int nt = 0; nt < 4; ++nt) {
                acc[mt][nt][0] += s4[0] * part[mt][nt][0];
                acc[mt][nt][1] += s4[1] * part[mt][nt][1];
                acc[mt][nt][2] += s4[2] * part[mt][nt][2];
                acc[mt][nt][3] += s4[3] * part[mt][nt][3];
            }
        }
    }

    // ---- epilogue: C/D layout col=lane&15, row=quad*4+reg ----
    #pragma unroll
    for (int mt = 0; mt < 4; ++mt)
        #pragma unroll
        for (int nt = 0; nt < 4; ++nt) {
            const long r  = row0 + wm + mt * 16 + quad * 4;
            const long cc = col0 + wn + nt * 16 + m;
            #pragma unroll
            for (int g = 0; g < 4; ++g)
                C[(r + g) * HIDDEN + cc] = acc[mt][nt][g];
        }
}

// ---------------------------------------------------------------------------
extern "C" void kernel_launch(void* const* d_in, const int* in_sizes, int n_in,
                              void* d_out, int out_size, void* d_ws, size_t ws_size,
                              hipStream_t stream) {
    const float* x  = (const float*)d_in[0];
    const float* z  = (const float*)d_in[1];
    const float* nw = (const float*)d_in[2];
    const float* w  = (const float*)d_in[3];
    float* out = (float*)d_out;

    // workspace layout (~49.3 MB)
    uint8_t* ws8   = (uint8_t*)d_ws;
    uint8_t* a_fp8 = ws8;                                   // 8192*4096   = 32 MiB
    uint8_t* w_fp8 = ws8 + (size_t)M_ROWS * HIDDEN;         // 4096*4096   = 16 MiB
    float*   a_scT = (float*)(w_fp8 + (size_t)HIDDEN * HIDDEN);      // 1 MiB [kg][row]
    float*   w_sc  = a_scT + (size_t)NGRP * M_ROWS;                  // 4 KiB

    act_quant_kernel<<<M_ROWS * NGRP / 8, 256, 0, stream>>>(
        (const float4_t*)x, (const float4_t*)z, nw, (uint32_t*)a_fp8, a_scT);
    w_quant_kernel<<<dim3(NGRP, NGRP), 256, 0, stream>>>(w, w_fp8, w_sc);
    gemm_fp8_scaled<<<dim3(M_ROWS / 128, HIDDEN / 128), 256, 0, stream>>>(
        a_fp8, a_scT, w_fp8, w_sc, out);
}